// Round 13
// baseline (3488.813 us; speedup 1.0000x reference)
//
#include <hip/hip_runtime.h>

#define BB 64
#define TT 512
#define EE 128
#define HH 512
#define NGRP 4
#define BG 16
#define JW 16
#define NSLOT 132
#define LDH 520   // 512 + 8 fp16 pad
#define LDE 136   // 128 + 8

typedef _Float16 f16;
typedef f16 f16x8 __attribute__((ext_vector_type(8)));
typedef float floatx4 __attribute__((ext_vector_type(4)));
typedef unsigned u32x4 __attribute__((ext_vector_type(4)));
typedef unsigned long long u64;

__device__ __forceinline__ float sigmf(float x) { return 1.f / (1.f + __expf(-x)); }
__device__ __forceinline__ float tanhfast(float x) { return 2.f / (1.f + __expf(-2.f * x)) - 1.f; }

// ---------------- slot map ----------------
__global__ __launch_bounds__(64) void build_map(const int* __restrict__ bnd,
                                                int* __restrict__ slotmap)
{
  __shared__ unsigned char need[TT];
  const int b = blockIdx.x;
  for (int i = threadIdx.x; i < TT; i += 64) need[i] = 0;
  __syncthreads();
  {
    const int w = threadIdx.x;
    const int iv = bnd[b * 65 + w];
    const int jv = bnd[b * 65 + w + 1];
    if (iv != -1 && jv != -1) {
      int ic = iv < 0 ? 0 : (iv > TT - 1 ? TT - 1 : iv);
      int jc = jv < 0 ? 0 : (jv > TT - 1 ? TT - 1 : jv);
      need[ic] = 1;
      need[jc] = 1;
    }
  }
  __syncthreads();
  if (threadIdx.x == 0) {
    int c = 0;
    for (int t = 0; t < TT; ++t) slotmap[b * TT + t] = need[t] ? (c++) : -1;
  }
}

// validate 8 tagged chunks in hv[], batched retry, scatter to sH
#define VALIDATE_SCATTER(HQ, TAGREP) do {                                            \
  unsigned bad = 0;                                                                  \
  _Pragma("unroll")                                                                  \
  for (int p = 0; p < 8; ++p) {                                                      \
    const unsigned d = ((hv[p][0] ^ (TAGREP)) | (hv[p][1] ^ (TAGREP)) |              \
                       (hv[p][2] ^ (TAGREP)) | (hv[p][3] ^ (TAGREP))) & 0xffff0000u; \
    bad |= (d ? 1u : 0u) << p;                                                       \
  }                                                                                  \
  while (__builtin_expect(bad != 0, 0)) {                                            \
    if (--budget < 0) break;                                                         \
    __builtin_amdgcn_s_sleep(4);                                                     \
    _Pragma("unroll")                                                                \
    for (int p = 0; p < 8; ++p)                                                      \
      if (bad & (1u << p))                                                           \
        asm volatile("global_load_dwordx4 %0, %1, off sc1"                           \
                     : "=v"(hv[p]) : "v"((HQ) + p * 1024 + tid * 4) : "memory");     \
    asm volatile("s_waitcnt vmcnt(0)" ::: "memory");                                 \
    unsigned nb = 0;                                                                 \
    _Pragma("unroll")                                                                \
    for (int p = 0; p < 8; ++p) {                                                    \
      const unsigned d = ((hv[p][0] ^ (TAGREP)) | (hv[p][1] ^ (TAGREP)) |            \
                         (hv[p][2] ^ (TAGREP)) | (hv[p][3] ^ (TAGREP))) & 0xffff0000u;\
      nb |= (d ? 1u : 0u) << p;                                                      \
    }                                                                                \
    bad = nb;                                                                        \
  }                                                                                  \
  __builtin_amdgcn_sched_barrier(0);                                                 \
  _Pragma("unroll")                                                                  \
  for (int p = 0; p < 8; ++p) {                                                      \
    const unsigned lo = (hv[p][0] & 0xffffu) | (hv[p][1] << 16);                     \
    const unsigned hi = (hv[p][2] & 0xffffu) | (hv[p][3] << 16);                     \
    const int i0 = p * 1024 + tid * 4;                                               \
    *(u64*)(sH + (i0 >> 9) * LDH + (i0 & 511)) = ((u64)hi << 32) | lo;               \
  }                                                                                  \
} while (0)

// one direction-step: x-MFMA + h-MFMA + LSTM epilogue -> hOut
#define PHASE_COMPUTE(SX, WH, WX, BSC, M4, CC, HHs) do {                             \
  floatx4 acc0 = {0.f,0.f,0.f,0.f}, acc1 = {0.f,0.f,0.f,0.f};                        \
  const f16* aX = (SX) + rloc * LDE + kg * 8;                                        \
  { f16x8 a0 = *(const f16x8*)(aX + 0);  f16x8 a1 = *(const f16x8*)(aX + 32);        \
    f16x8 a2 = *(const f16x8*)(aX + 64); f16x8 a3 = *(const f16x8*)(aX + 96);        \
    acc0 = __builtin_amdgcn_mfma_f32_16x16x32_f16(a0, (WX)[0], acc0, 0, 0, 0);       \
    acc1 = __builtin_amdgcn_mfma_f32_16x16x32_f16(a1, (WX)[1], acc1, 0, 0, 0);       \
    acc0 = __builtin_amdgcn_mfma_f32_16x16x32_f16(a2, (WX)[2], acc0, 0, 0, 0);       \
    acc1 = __builtin_amdgcn_mfma_f32_16x16x32_f16(a3, (WX)[3], acc1, 0, 0, 0); }     \
  const f16* aH = sH + rloc * LDH + kg * 8;                                          \
  _Pragma("unroll")                                                                  \
  for (int kk = 0; kk < 16; kk += 2) {                                               \
    f16x8 a0 = *(const f16x8*)(aH + kk * 32);                                        \
    f16x8 a1 = *(const f16x8*)(aH + (kk + 1) * 32);                                  \
    acc0 = __builtin_amdgcn_mfma_f32_16x16x32_f16(a0, (WH)[kk], acc0, 0, 0, 0);      \
    acc1 = __builtin_amdgcn_mfma_f32_16x16x32_f16(a1, (WH)[kk + 1], acc1, 0, 0, 0);  \
  }                                                                                  \
  floatx4 acc = acc0 + acc1;                                                         \
  _Pragma("unroll")                                                                  \
  for (int i = 0; i < 4; ++i) {                                                      \
    const float g0 = acc[i] + (BSC);                                                 \
    const float s1 = __shfl_xor(g0, 1, 64);                                          \
    const float s2 = __shfl_xor(g0, 2, 64);                                          \
    const float s3 = __shfl_xor(s1, 2, 64);                                          \
    float vi, vf, vg, vo;                                                            \
    if (q == 0)      { vi = g0; vf = s1; vg = s2; vo = s3; }                         \
    else if (q == 1) { vi = s1; vf = g0; vg = s3; vo = s2; }                         \
    else if (q == 2) { vi = s2; vf = s3; vg = g0; vo = s1; }                         \
    else             { vi = s3; vf = s2; vg = s1; vo = g0; }                         \
    const float ig = sigmf(vi);                                                      \
    const float fg = sigmf(vf);                                                      \
    const float gt = tanhfast(vg);                                                   \
    const float og = sigmf(vo);                                                      \
    const float cn = fg * (CC)[i] + ig * gt;                                         \
    const float hn = og * tanhfast(cn);                                              \
    const float m = (M4)[i];                                                         \
    (CC)[i] = m > 0.f ? cn : (CC)[i];                                                \
    float hk = m > 0.f ? hn : (HHs)[i];                                              \
    const f16 h16 = (f16)hk;                                                         \
    (HHs)[i] = (float)h16;                                                           \
  }                                                                                  \
  { const float hq_ = (q == 0) ? (HHs)[0] : (q == 1) ? (HHs)[1]                      \
                     : (q == 2) ? (HHs)[2] : (HHs)[3];                               \
    hOut[(mbase + q) * JW + jloc] = (f16)hq_; }                                      \
} while (0)

// wave0 export of hOut slice: tagged h_g (if NS<TT) + hist (always, trash slot)
#define EXPORT_SLICE(HQN, DBIT, MB, SLB, NS) do {                                    \
  if (tid < 64) {                                                                    \
    const int c0 = (tid & 3) * 4;                                                    \
    const u64 hv8 = *(const u64*)(hOut + blw * JW + c0);                             \
    if ((NS) < TT) {                                                                 \
      const unsigned tg2 = (unsigned)((((NS) << 1) | (DBIT))) << 16;                 \
      u32x4 ev;                                                                      \
      ev[0] = tg2 | (unsigned)(hv8 & 0xffff);                                        \
      ev[1] = tg2 | (unsigned)((hv8 >> 16) & 0xffff);                                \
      ev[2] = tg2 | (unsigned)((hv8 >> 32) & 0xffff);                                \
      ev[3] = tg2 | (unsigned)((hv8 >> 48) & 0xffff);                                \
      unsigned* hdst = (HQN) + blw * HH + slice * JW + c0;                           \
      asm volatile("global_store_dwordx4 %0, %1, off sc1" :: "v"(hdst), "v"(ev)      \
                   : "memory");                                                      \
    }                                                                                \
    const int slotStore = (SLB) >= 0 ? (SLB) : (NSLOT - 1);                          \
    const u64 hvm = ((SLB) >= 0 && (MB) > 0.f) ? hv8 : 0ULL;                         \
    u64* hdst2 = (u64*)(hist + ((size_t)((DBIT) * BB + gb + blw) * NSLOT             \
                        + slotStore) * HH + slice * JW + c0);                        \
    asm volatile("global_store_dwordx2 %0, %1, off" :: "v"(hdst2), "v"(hvm)          \
                 : "memory");                                                        \
  }                                                                                  \
} while (0)

// ---------------- fused bidirectional persistent LSTM scan ----------------
// 128 blocks x 256 threads; block = (grp = bid>>5, slice = bid&31), BOTH dirs.
// Tagged u32 exchange ((step<<1|dir)<<16 | f16), no flags. Loads for each phase
// are issued one full opposite-phase (~1us) after peers export that data, so
// their L3 RT hides under real compute; tags + batched budgeted retry backstop.
__global__ __launch_bounds__(256, 1) void lstm_scan(
    const int* __restrict__ ids, const int* __restrict__ maskI,
    const float* __restrict__ emb,
    const float* __restrict__ Wih_f, const float* __restrict__ Whh_f, const float* __restrict__ b_f,
    const float* __restrict__ Wih_b, const float* __restrict__ Whh_b, const float* __restrict__ b_b,
    const int* __restrict__ slotmap,
    unsigned* __restrict__ h_g,   // [2 parity][2 dir][NGRP][BG][HH] u32 (tag|f16)
    f16* __restrict__ hist)       // [2 dir][BB][NSLOT][HH] f16
{
  __shared__ f16 sH[BG * LDH];
  __shared__ f16 sXf[BG * LDE];
  __shared__ f16 sXb[BG * LDE];
  __shared__ f16 hOut[BG * JW];

  const int tid = threadIdx.x;
  const int bid = blockIdx.x;
  const int grp = bid >> 5;
  const int slice = bid & 31;
  const int lane = tid & 63;
  const int wave = tid >> 6;
  const int rloc = lane & 15;
  const int kg   = lane >> 4;
  const int rglob = wave * 16 + rloc;  // gate-row in slice, r = jloc*4 + q
  const int jloc  = rglob >> 2;
  const int q     = rglob & 3;         // 0=i,1=f,2=g,3=o
  const int mbase = kg * 4;
  const int growL = q * HH + slice * JW + jloc;
  const int gb = grp * BG;
  const int blw = tid >> 2;            // wave0 export batch (tid<64)

  // --- weights for BOTH directions, register-resident (fp32 -> fp16) ---
  f16x8 whf[16], whb[16], wxf[4], wxb[4];
  {
    const float* wf = Whh_f + (size_t)growL * HH + kg * 8;
    const float* wb = Whh_b + (size_t)growL * HH + kg * 8;
    #pragma unroll
    for (int kk = 0; kk < 16; ++kk) {
      float4 a0 = *(const float4*)(wf + kk * 32);
      float4 a1 = *(const float4*)(wf + kk * 32 + 4);
      float4 c0 = *(const float4*)(wb + kk * 32);
      float4 c1 = *(const float4*)(wb + kk * 32 + 4);
      f16x8 v, w;
      v[0]=(f16)a0.x; v[1]=(f16)a0.y; v[2]=(f16)a0.z; v[3]=(f16)a0.w;
      v[4]=(f16)a1.x; v[5]=(f16)a1.y; v[6]=(f16)a1.z; v[7]=(f16)a1.w;
      w[0]=(f16)c0.x; w[1]=(f16)c0.y; w[2]=(f16)c0.z; w[3]=(f16)c0.w;
      w[4]=(f16)c1.x; w[5]=(f16)c1.y; w[6]=(f16)c1.z; w[7]=(f16)c1.w;
      whf[kk] = v; whb[kk] = w;
    }
    const float* xf = Wih_f + (size_t)growL * EE + kg * 8;
    const float* xb = Wih_b + (size_t)growL * EE + kg * 8;
    #pragma unroll
    for (int kk = 0; kk < 4; ++kk) {
      float4 a0 = *(const float4*)(xf + kk * 32);
      float4 a1 = *(const float4*)(xf + kk * 32 + 4);
      float4 c0 = *(const float4*)(xb + kk * 32);
      float4 c1 = *(const float4*)(xb + kk * 32 + 4);
      f16x8 v, w;
      v[0]=(f16)a0.x; v[1]=(f16)a0.y; v[2]=(f16)a0.z; v[3]=(f16)a0.w;
      v[4]=(f16)a1.x; v[5]=(f16)a1.y; v[6]=(f16)a1.z; v[7]=(f16)a1.w;
      w[0]=(f16)c0.x; w[1]=(f16)c0.y; w[2]=(f16)c0.z; w[3]=(f16)c0.w;
      w[4]=(f16)c1.x; w[5]=(f16)c1.y; w[6]=(f16)c1.z; w[7]=(f16)c1.w;
      wxf[kk] = v; wxb[kk] = w;
    }
  }
  const float bscf = b_f[growL];
  const float bscb = b_b[growL];

  float ccf[4] = {0,0,0,0}, hhf[4] = {0,0,0,0};
  float ccb[4] = {0,0,0,0}, hhb[4] = {0,0,0,0};
  int budget = 100000;

  const int xrow = tid >> 4;
  const int xc0 = (tid & 15) * 8;

  float m4f[4], m4b[4], m4nf[4] = {0,0,0,0}, m4nb[4] = {0,0,0,0};
  float mBf = 0.f, mBb = 0.f, mBnf = 0.f, mBnb = 0.f;
  int slBf = -1, slBb = -1, slBnf = -1, slBnb = -1;
  int idxNf, idxNb;
  u32x4 hv[8];
  u32x4 pxf0, pxf1, pxb0, pxb1;

  // ---- prologue ----
  {
    #pragma unroll
    for (int i = 0; i < 4; ++i) {
      m4f[i] = (float)maskI[(gb + mbase + i) * TT + 0];
      m4b[i] = (float)maskI[(gb + mbase + i) * TT + TT - 1];
    }
    if (tid < 64) {
      mBf = (float)maskI[(gb + blw) * TT + 0];
      slBf = slotmap[(gb + blw) * TT + 0];
      mBb = (float)maskI[(gb + blw) * TT + TT - 1];
      slBb = slotmap[(gb + blw) * TT + TT - 1];
    }
    idxNf = ids[(gb + xrow) * TT + 1];
    idxNb = ids[(gb + xrow) * TT + TT - 2];
    for (int e = tid; e < BG * 64; e += 256) {
      const int row = e >> 6, ch = e & 63;
      uint4 z = make_uint4(0u, 0u, 0u, 0u);
      *(uint4*)(sH + row * LDH + ch * 8) = z;
    }
    const int i0 = ids[(gb + xrow) * TT + 0];
    const int i1 = ids[(gb + xrow) * TT + TT - 1];
    float4 x0 = *(const float4*)(emb + (size_t)i0 * EE + xc0);
    float4 x1 = *(const float4*)(emb + (size_t)i0 * EE + xc0 + 4);
    float4 y0 = *(const float4*)(emb + (size_t)i1 * EE + xc0);
    float4 y1 = *(const float4*)(emb + (size_t)i1 * EE + xc0 + 4);
    f16x8 xv, yv;
    xv[0]=(f16)x0.x; xv[1]=(f16)x0.y; xv[2]=(f16)x0.z; xv[3]=(f16)x0.w;
    xv[4]=(f16)x1.x; xv[5]=(f16)x1.y; xv[6]=(f16)x1.z; xv[7]=(f16)x1.w;
    yv[0]=(f16)y0.x; yv[1]=(f16)y0.y; yv[2]=(f16)y0.z; yv[3]=(f16)y0.w;
    yv[4]=(f16)y1.x; yv[5]=(f16)y1.y; yv[6]=(f16)y1.z; yv[7]=(f16)y1.w;
    *(f16x8*)(sXf + xrow * LDE + xc0) = xv;
    *(f16x8*)(sXb + xrow * LDE + xc0) = yv;
  }
  __syncthreads();

  for (int s = 0; s < TT; ++s) {
    const int ns = s + 1;
    unsigned* hqF  = h_g + (((size_t)(s & 1) * 2 + 0) * NGRP + grp) * BG * HH;
    unsigned* hqB  = h_g + (((size_t)(s & 1) * 2 + 1) * NGRP + grp) * BG * HH;
    unsigned* hqFn = h_g + (((size_t)(ns & 1) * 2 + 0) * NGRP + grp) * BG * HH;
    unsigned* hqBn = h_g + (((size_t)(ns & 1) * 2 + 1) * NGRP + grp) * BG * HH;

    // ---- S1: wait (counted for wave0: 2 newest = prev B exports), validate F(s),
    //          scatter -> sH; commit x_b(s); rotate b-regs ----
    if (s > 0) {
      if (wave == 0) asm volatile("s_waitcnt vmcnt(2)" ::: "memory");
      else           asm volatile("s_waitcnt vmcnt(0)" ::: "memory");
      __builtin_amdgcn_sched_barrier(0);
      const unsigned tagF = (unsigned)((s << 1) | 0) << 16;
      VALIDATE_SCATTER(hqF, tagF);
      {
        f16x8 xv;
        xv[0]=(f16)__uint_as_float(pxb0[0]); xv[1]=(f16)__uint_as_float(pxb0[1]);
        xv[2]=(f16)__uint_as_float(pxb0[2]); xv[3]=(f16)__uint_as_float(pxb0[3]);
        xv[4]=(f16)__uint_as_float(pxb1[0]); xv[5]=(f16)__uint_as_float(pxb1[1]);
        xv[6]=(f16)__uint_as_float(pxb1[2]); xv[7]=(f16)__uint_as_float(pxb1[3]);
        *(f16x8*)(sXb + xrow * LDE + xc0) = xv;
      }
      #pragma unroll
      for (int i = 0; i < 4; ++i) m4b[i] = m4nb[i];
      mBb = mBnb; slBb = slBnb;
    }
    __syncthreads();                     // S2

    // ---- S3: issue B(s) h-loads (flew past peers' exports ~1 phase ago)
    //          + f-prefetch(ns) ----
    if (s > 0) {
      #pragma unroll
      for (int p = 0; p < 8; ++p)
        asm volatile("global_load_dwordx4 %0, %1, off sc1"
                     : "=v"(hv[p]) : "v"(hqB + p * 1024 + tid * 4) : "memory");
    }
    if (ns < TT) {
      const int idxC = idxNf;
      if (ns + 1 < TT) idxNf = ids[(gb + xrow) * TT + ns + 1];
      const float* ep = emb + (size_t)idxC * EE + xc0;
      asm volatile("global_load_dwordx4 %0, %1, off" : "=v"(pxf0) : "v"(ep) : "memory");
      asm volatile("global_load_dwordx4 %0, %1, off" : "=v"(pxf1) : "v"(ep + 4) : "memory");
      #pragma unroll
      for (int i = 0; i < 4; ++i)
        m4nf[i] = (float)maskI[(gb + mbase + i) * TT + ns];
      if (tid < 64) {
        mBnf = (float)maskI[(gb + blw) * TT + ns];
        slBnf = slotmap[(gb + blw) * TT + ns];
      }
    }

    // ---- S4: F(s) compute ----
    PHASE_COMPUTE(sXf, whf, wxf, bscf, m4f, ccf, hhf);
    __syncthreads();                     // S5

    // ---- S6a: wait all (only loads outstanding), validate B(s), scatter ----
    asm volatile("s_waitcnt vmcnt(0)" ::: "memory");
    __builtin_amdgcn_sched_barrier(0);
    if (s > 0) {
      const unsigned tagB = (unsigned)((s << 1) | 1) << 16;
      VALIDATE_SCATTER(hqB, tagB);
    }
    // ---- S6b: export h_f(ns) + hist_f ----
    EXPORT_SLICE(hqFn, 0, mBf, slBf, ns);
    // ---- S6c: commit x_f(ns); rotate f-regs ----
    if (ns < TT) {
      f16x8 xv;
      xv[0]=(f16)__uint_as_float(pxf0[0]); xv[1]=(f16)__uint_as_float(pxf0[1]);
      xv[2]=(f16)__uint_as_float(pxf0[2]); xv[3]=(f16)__uint_as_float(pxf0[3]);
      xv[4]=(f16)__uint_as_float(pxf1[0]); xv[5]=(f16)__uint_as_float(pxf1[1]);
      xv[6]=(f16)__uint_as_float(pxf1[2]); xv[7]=(f16)__uint_as_float(pxf1[3]);
      *(f16x8*)(sXf + xrow * LDE + xc0) = xv;
    }
    #pragma unroll
    for (int i = 0; i < 4; ++i) m4f[i] = m4nf[i];
    mBf = mBnf; slBf = slBnf;
    __syncthreads();                     // S8

    // ---- S9: issue F(ns) h-loads + b-prefetch(ns) ----
    if (ns < TT) {
      #pragma unroll
      for (int p = 0; p < 8; ++p)
        asm volatile("global_load_dwordx4 %0, %1, off sc1"
                     : "=v"(hv[p]) : "v"(hqFn + p * 1024 + tid * 4) : "memory");
      const int idxC = idxNb;
      if (ns + 1 < TT) idxNb = ids[(gb + xrow) * TT + (TT - 2 - ns)];
      const float* ep = emb + (size_t)idxC * EE + xc0;
      asm volatile("global_load_dwordx4 %0, %1, off" : "=v"(pxb0) : "v"(ep) : "memory");
      asm volatile("global_load_dwordx4 %0, %1, off" : "=v"(pxb1) : "v"(ep + 4) : "memory");
      #pragma unroll
      for (int i = 0; i < 4; ++i)
        m4nb[i] = (float)maskI[(gb + mbase + i) * TT + TT - 1 - ns];
      if (tid < 64) {
        mBnb = (float)maskI[(gb + blw) * TT + TT - 1 - ns];
        slBnb = slotmap[(gb + blw) * TT + TT - 1 - ns];
      }
    }

    // ---- S10: B(s) compute ----
    PHASE_COMPUTE(sXb, whb, wxb, bscb, m4b, ccb, hhb);
    __syncthreads();                     // S11

    // ---- S12: export h_b(ns) + hist_b ----
    EXPORT_SLICE(hqBn, 1, mBb, slBb, ns);
  }
}

// ---------------- gather boundary outputs ----------------
__global__ __launch_bounds__(256) void gather_out(
    const int* __restrict__ bnd, const int* __restrict__ slotmap,
    const f16* __restrict__ hist, float* __restrict__ out)
{
  const int bw = blockIdx.x;
  const int b = bw >> 6;
  const int w = bw & 63;
  const int k = threadIdx.x * 8;
  const int iv = bnd[b * 65 + w];
  const int jv = bnd[b * 65 + w + 1];
  const bool valid = (iv != -1) && (jv != -1);
  float* dst = out + (size_t)bw * 2048 + k;
  if (valid) {
    const int seg = k >> 9;                    // 0:h_f(i) 1:h_b(i) 2:h_f(j) 3:h_b(j)
    int ts = (seg < 2) ? iv : jv;
    ts = ts < 0 ? 0 : (ts > TT - 1 ? TT - 1 : ts);
    const int dirn = seg & 1;
    const int slot = slotmap[b * TT + ts];
    const f16* src = hist + ((size_t)(dirn * BB + b) * NSLOT + slot) * HH + (k & 511);
    f16x8 v = *(const f16x8*)src;
    float4 o0 = make_float4((float)v[0], (float)v[1], (float)v[2], (float)v[3]);
    float4 o1 = make_float4((float)v[4], (float)v[5], (float)v[6], (float)v[7]);
    *(float4*)dst = o0;
    *(float4*)(dst + 4) = o1;
  } else {
    float4 z = make_float4(0.f, 0.f, 0.f, 0.f);
    *(float4*)dst = z;
    *(float4*)(dst + 4) = z;
  }
}

extern "C" void kernel_launch(void* const* d_in, const int* in_sizes, int n_in,
                              void* d_out, int out_size, void* d_ws, size_t ws_size,
                              hipStream_t stream)
{
  (void)in_sizes; (void)n_in; (void)out_size; (void)ws_size;
  const int* ids     = (const int*)d_in[0];
  const int* maskI   = (const int*)d_in[1];
  const int* bnd     = (const int*)d_in[2];
  const float* emb   = (const float*)d_in[3];
  const float* Wih_f = (const float*)d_in[4];
  const float* Whh_f = (const float*)d_in[5];
  const float* b_f   = (const float*)d_in[6];
  const float* Wih_b = (const float*)d_in[7];
  const float* Whh_b = (const float*)d_in[8];
  const float* b_b   = (const float*)d_in[9];

  char* ws = (char*)d_ws;
  int* slotmap    = (int*)ws;                          // 128 KiB
  unsigned* h_g   = (unsigned*)(ws + 131072);          // 1 MiB tagged ping-pong
  f16* hist       = (f16*)(ws + 131072 + 1048576);     // ~17 MiB

  hipMemsetAsync(h_g, 0, 1048576, stream);             // tags := 0 (valid tags >= 2)
  build_map<<<dim3(BB), dim3(64), 0, stream>>>(bnd, slotmap);
  lstm_scan<<<dim3(NGRP * 32), dim3(256), 0, stream>>>(ids, maskI, emb,
      Wih_f, Whh_f, b_f, Wih_b, Whh_b, b_b, slotmap, h_g, hist);
  gather_out<<<dim3(BB * 64), dim3(256), 0, stream>>>(bnd, slotmap, hist, (float*)d_out);
}